// Round 5
// baseline (14382.117 us; speedup 1.0000x reference)
//
#include <hip/hip_runtime.h>
#include <cstdint>
#include <cstddef>

#define NN 5000     // nodes per batch block
#define EE 40000    // edges per batch block
#define BATCH 8
#define SS 12
#define FF 16
#define HH 128
#define TOTAL 40000 // BATCH*NN
#define CC 4

typedef __attribute__((ext_vector_type(8))) short short8;   // 8 bf16 (4 VGPRs)
typedef __attribute__((ext_vector_type(4))) float f32x4;    // 4 fp32

__device__ __forceinline__ unsigned short f2bf(float f) {
  union { float f; unsigned u; } v; v.f = f;
  unsigned r = v.u + 0x7fff + ((v.u >> 16) & 1);  // RTNE
  return (unsigned short)(r >> 16);
}
__device__ __forceinline__ float bf2f(unsigned short b) {
  union { unsigned u; float f; } v; v.u = ((unsigned)b) << 16;
  return v.f;
}
__device__ __forceinline__ float bflo(unsigned v) {
  union { unsigned u; float f; } x; x.u = v << 16; return x.f;
}
__device__ __forceinline__ float bfhi(unsigned v) {
  union { unsigned u; float f; } x; x.u = v & 0xffff0000u; return x.f;
}
__device__ __forceinline__ unsigned xcc_id() {
  unsigned x;
  asm("s_getreg_b32 %0, hwreg(HW_REG_XCC_ID)" : "=s"(x));
  return x & 7;
}

// ---------------- graph preprocessing (once per launch) ----------------

__global__ void deg_cnt_kernel(const int* __restrict__ ei, const float* __restrict__ ew,
                               float* __restrict__ deg, int* __restrict__ cnt) {
  int e = blockIdx.x * 256 + threadIdx.x;
  if (e < EE) {
    int col = ei[EE + e];
    atomicAdd(&deg[col], ew[e]);
    atomicAdd(&cnt[col], 1);
  }
}

__global__ void dis_kernel(const float* __restrict__ deg, float* __restrict__ dis) {
  int n = blockIdx.x * 256 + threadIdx.x;
  if (n < NN) dis[n] = rsqrtf(deg[n] + 1.0f);  // +1: self-loop weight
}

__global__ void scan_kernel(const int* __restrict__ cnt, int* __restrict__ offs) {
  __shared__ int part[256];
  const int CH = (NN + 255) / 256; // 20
  int tid = threadIdx.x;
  int base = tid * CH;
  int s = 0;
  for (int i = 0; i < CH; i++) { int idx = base + i; if (idx < NN) s += cnt[idx]; }
  part[tid] = s;
  __syncthreads();
  for (int off = 1; off < 256; off <<= 1) {
    int v = (tid >= off) ? part[tid - off] : 0;
    __syncthreads();
    part[tid] += v;
    __syncthreads();
  }
  int run = (tid == 0) ? 0 : part[tid - 1];
  for (int i = 0; i < CH; i++) {
    int idx = base + i;
    if (idx < NN) { offs[idx] = run; run += cnt[idx]; }
  }
  if (tid == 255) offs[NN] = run;
}

__global__ void fill_csr_kernel(const int* __restrict__ ei, const float* __restrict__ ew,
                                const float* __restrict__ dis, const int* __restrict__ offs,
                                int* __restrict__ cursor, int* __restrict__ csr_src,
                                float* __restrict__ csr_w) {
  int e = blockIdx.x * 256 + threadIdx.x;
  if (e < EE) {
    int row = ei[e], col = ei[EE + e];
    int pos = offs[col] + atomicAdd(&cursor[col], 1);
    csr_src[pos] = row;
    csr_w[pos] = dis[row] * ew[e] * dis[col];
  }
}

// ---------------- weight prepack: fp32 [k][n] -> bf16 MFMA b-frag order ----------------

__global__ void prepack_kernel(const float* __restrict__ convW, unsigned short* __restrict__ Wp) {
  int idx = blockIdx.x * 256 + threadIdx.x;  // 6*8*8*64 = 24576
  int lane = idx & 63;
  int ks = (idx >> 6) & 7;
  int nt = (idx >> 9) & 7;
  int g = idx >> 12;
  const float* W = convW + (size_t)g * 256 * 128;
  int n = nt * 16 + (lane & 15);
  int k0 = ks * 32 + (lane >> 4) * 8;
  unsigned short v[8];
#pragma unroll
  for (int j = 0; j < 8; j++) v[j] = f2bf(W[(size_t)(k0 + j) * 128 + n]);
  *(uint4*)(Wp + (size_t)idx * 8) = *(const uint4*)v;
}

// ---------------- lin_in: xt = relu(x_t @ Win + bin), bf16 out, row = n*8+bb ----------------

__global__ __launch_bounds__(256) void lin_in_kernel(const float* __restrict__ x_seq,
                                                     const float* __restrict__ W,
                                                     const float* __restrict__ b,
                                                     unsigned short* __restrict__ xt, int t) {
  int idx = blockIdx.x * 256 + threadIdx.x;   // over TOTAL*32
  int row = idx >> 5, fq = idx & 31;          // feats 4fq..4fq+3
  int n = row >> 3, bb = row & 7;
  const float* xp = x_seq + (((size_t)bb * SS + t) * NN + n) * FF;
  float4 a = *(const float4*)&b[fq * 4];
#pragma unroll
  for (int ff = 0; ff < FF; ff++) {
    float xv = xp[ff];
    float4 w = *(const float4*)&W[ff * HH + fq * 4];
    a.x += xv * w.x; a.y += xv * w.y; a.z += xv * w.z; a.w += xv * w.w;
  }
  uint2 o;
  o.x = (unsigned)f2bf(fmaxf(a.x, 0.f)) | ((unsigned)f2bf(fmaxf(a.y, 0.f)) << 16);
  o.y = (unsigned)f2bf(fmaxf(a.z, 0.f)) | ((unsigned)f2bf(fmaxf(a.w, 0.f)) << 16);
  *(uint2*)&xt[(size_t)row * 128 + fq * 4] = o;
}

// ---------------- bf16 MFMA GEMM ----------------

template <int NTW>
__global__ __launch_bounds__(256) void gemm_mfma(const unsigned short* __restrict__ A1,
                                                 const unsigned short* __restrict__ A2,
                                                 const unsigned short* __restrict__ Wp,
                                                 unsigned short* __restrict__ outR,
                                                 unsigned short* __restrict__ outU) {
  __shared__ unsigned short As[64 * 264];  // 64 rows x 256 K, +8 pad
  int rowBase = blockIdx.x * 64;
  int tid = threadIdx.x;
  for (int c = tid; c < 2048; c += 256) {
    int row = c >> 5; int rest = c & 31; int half = rest >> 4; int sub = rest & 15;
    const unsigned short* src = (half ? A2 : A1) + ((size_t)(rowBase + row) * 128 + sub * 8);
    *(uint4*)&As[row * 264 + half * 128 + sub * 8] = *(const uint4*)src;
  }
  __syncthreads();
  int wv = tid >> 6, lane = tid & 63;
  int m = lane & 15, q = lane >> 4;
  f32x4 acc[4][NTW];
#pragma unroll
  for (int i = 0; i < 4; i++)
#pragma unroll
    for (int j = 0; j < NTW; j++) acc[i][j] = (f32x4)(0.0f);
  const unsigned short* wbase = Wp + ((size_t)(wv * NTW) * 8 * 64 + lane) * 8;
#pragma unroll
  for (int ks = 0; ks < 8; ks++) {
    short8 a[4];
#pragma unroll
    for (int mt = 0; mt < 4; mt++)
      a[mt] = *(const short8*)&As[(mt * 16 + m) * 264 + ks * 32 + q * 8];
#pragma unroll
    for (int nt = 0; nt < NTW; nt++) {
      short8 b = *(const short8*)(wbase + (size_t)(nt * 8 + ks) * 64 * 8);
#pragma unroll
      for (int mt = 0; mt < 4; mt++)
        acc[mt][nt] = __builtin_amdgcn_mfma_f32_16x16x32_bf16(a[mt], b, acc[mt][nt], 0, 0, 0);
    }
  }
#pragma unroll
  for (int mt = 0; mt < 4; mt++)
#pragma unroll
    for (int nt = 0; nt < NTW; nt++) {
      int col = (wv * NTW + nt) * 16 + m;
      unsigned short* op = (col < 128) ? (outR + col) : (outU + (col - 128));
#pragma unroll
      for (int i = 0; i < 4; i++) {
        int row = rowBase + mt * 16 + q * 4 + i;
        op[(size_t)row * 128] = f2bf(acc[mt][nt][i]);
      }
    }
}

// ---------------- gates aggregation: batch-chunked, XCD-affine work queue ----------------
// Chunk c = batch. Work item = (bb=c, group of 4 nodes); wave = 1 node, lanes 0-31 -> GR
// cols lane*4, lanes 32-63 -> GU. Per-XCD hot set = GR|GU slice for one batch = 2.56 MB.

__global__ __launch_bounds__(256) void scatter_gates_kernel(
    const unsigned short* __restrict__ GR, const unsigned short* __restrict__ GU,
    const int* __restrict__ offs, const int* __restrict__ csr_src,
    const float* __restrict__ csr_w, const float* __restrict__ dis,
    const float* __restrict__ bRU, const unsigned short* __restrict__ h,
    unsigned short* __restrict__ rh, unsigned short* __restrict__ u,
    int* __restrict__ q) {
  __shared__ int sg;
  int tid = threadIdx.x;
  int wv = tid >> 6, lane = tid & 63;
  int half = lane >> 5;
  int col = (lane & 31) << 2;
  const unsigned short* G = half ? GU : GR;
  const float* bias = bRU + half * 128 + col;
  float b0 = bias[0], b1 = bias[1], b2 = bias[2], b3 = bias[3];
  unsigned xcc = xcc_id();
  for (int attempt = 0; attempt < 8; attempt++) {
    int c = (xcc + attempt) & 7;
    int* qc = q + c;
    while (true) {
      if (tid == 0) sg = atomicAdd(qc, 1);
      __syncthreads();
      int g = sg;
      __syncthreads();
      if (g >= NN / 4) break;
      int n = g * 4 + wv;
      int bb = c;
      float sn = dis[n]; sn *= sn;
      size_t rowSelf = (size_t)(n << 3) + bb;
      uint2 gv = *(const uint2*)&G[rowSelf * 128 + col];
      float a0 = sn * bflo(gv.x), a1 = sn * bfhi(gv.x);
      float a2 = sn * bflo(gv.y), a3 = sn * bfhi(gv.y);
      int e0 = offs[n], e1 = offs[n + 1];
      int e = e0;
      for (; e + 1 < e1; e += 2) {
        int s0 = csr_src[e], s1 = csr_src[e + 1];
        float w0 = csr_w[e], w1 = csr_w[e + 1];
        uint2 ga = *(const uint2*)&G[(((size_t)s0 << 3) + bb) * 128 + col];
        uint2 gb = *(const uint2*)&G[(((size_t)s1 << 3) + bb) * 128 + col];
        a0 += w0 * bflo(ga.x); a1 += w0 * bfhi(ga.x);
        a2 += w0 * bflo(ga.y); a3 += w0 * bfhi(ga.y);
        a0 += w1 * bflo(gb.x); a1 += w1 * bfhi(gb.x);
        a2 += w1 * bflo(gb.y); a3 += w1 * bfhi(gb.y);
      }
      if (e < e1) {
        int s0 = csr_src[e];
        float w0 = csr_w[e];
        uint2 ga = *(const uint2*)&G[(((size_t)s0 << 3) + bb) * 128 + col];
        a0 += w0 * bflo(ga.x); a1 += w0 * bfhi(ga.x);
        a2 += w0 * bflo(ga.y); a3 += w0 * bfhi(ga.y);
      }
      float v0 = 1.0f / (1.0f + __expf(-(a0 + b0)));
      float v1 = 1.0f / (1.0f + __expf(-(a1 + b1)));
      float v2 = 1.0f / (1.0f + __expf(-(a2 + b2)));
      float v3 = 1.0f / (1.0f + __expf(-(a3 + b3)));
      if (half == 0) {
        unsigned long long hv = __builtin_nontemporal_load(
            (const unsigned long long*)&h[rowSelf * 128 + col]);
        v0 *= bflo((unsigned)hv); v1 *= bfhi((unsigned)hv);
        v2 *= bflo((unsigned)(hv >> 32)); v3 *= bfhi((unsigned)(hv >> 32));
        unsigned lo = (unsigned)f2bf(v0) | ((unsigned)f2bf(v1) << 16);
        unsigned hi = (unsigned)f2bf(v2) | ((unsigned)f2bf(v3) << 16);
        __builtin_nontemporal_store(((unsigned long long)hi << 32) | lo,
                                    (unsigned long long*)&rh[rowSelf * 128 + col]);
      } else {
        unsigned lo = (unsigned)f2bf(v0) | ((unsigned)f2bf(v1) << 16);
        unsigned hi = (unsigned)f2bf(v2) | ((unsigned)f2bf(v3) << 16);
        __builtin_nontemporal_store(((unsigned long long)hi << 32) | lo,
                                    (unsigned long long*)&u[rowSelf * 128 + col]);
      }
    }
  }
}

// ---------------- candidate aggregation + GRU update: batch-chunked, XCD-affine ----------------
// Work item = (bb=c, group of 8 nodes); wave = 2 nodes x 32 lanes (128 cols).

__global__ __launch_bounds__(256) void scatter_c_update_kernel(
    const unsigned short* __restrict__ Cp, const int* __restrict__ offs,
    const int* __restrict__ csr_src, const float* __restrict__ csr_w,
    const float* __restrict__ dis, const float* __restrict__ bC,
    const unsigned short* __restrict__ u, unsigned short* __restrict__ h,
    int* __restrict__ q) {
  __shared__ int sg;
  int tid = threadIdx.x;
  int wv = tid >> 6, lane = tid & 63;
  int nh = lane >> 5;             // node-in-pair
  int col = (lane & 31) << 2;
  const float* bp = bC + col;
  float b0 = bp[0], b1 = bp[1], b2 = bp[2], b3 = bp[3];
  unsigned xcc = xcc_id();
  for (int attempt = 0; attempt < 8; attempt++) {
    int c = (xcc + attempt) & 7;
    int* qc = q + c;
    while (true) {
      if (tid == 0) sg = atomicAdd(qc, 1);
      __syncthreads();
      int g = sg;
      __syncthreads();
      if (g >= NN / 8) break;
      int n = g * 8 + wv * 2 + nh;
      int bb = c;
      float sn = dis[n]; sn *= sn;
      size_t rowSelf = (size_t)(n << 3) + bb;
      uint2 gv = *(const uint2*)&Cp[rowSelf * 128 + col];
      float a0 = sn * bflo(gv.x), a1 = sn * bfhi(gv.x);
      float a2 = sn * bflo(gv.y), a3 = sn * bfhi(gv.y);
      int e0 = offs[n], e1 = offs[n + 1];
      int e = e0;
      for (; e + 1 < e1; e += 2) {
        int s0 = csr_src[e], s1 = csr_src[e + 1];
        float w0 = csr_w[e], w1 = csr_w[e + 1];
        uint2 ga = *(const uint2*)&Cp[(((size_t)s0 << 3) + bb) * 128 + col];
        uint2 gb = *(const uint2*)&Cp[(((size_t)s1 << 3) + bb) * 128 + col];
        a0 += w0 * bflo(ga.x); a1 += w0 * bfhi(ga.x);
        a2 += w0 * bflo(ga.y); a3 += w0 * bfhi(ga.y);
        a0 += w1 * bflo(gb.x); a1 += w1 * bfhi(gb.x);
        a2 += w1 * bflo(gb.y); a3 += w1 * bfhi(gb.y);
      }
      if (e < e1) {
        int s0 = csr_src[e];
        float w0 = csr_w[e];
        uint2 ga = *(const uint2*)&Cp[(((size_t)s0 << 3) + bb) * 128 + col];
        a0 += w0 * bflo(ga.x); a1 += w0 * bfhi(ga.x);
        a2 += w0 * bflo(ga.y); a3 += w0 * bfhi(ga.y);
      }
      float c0 = 1.0f - 2.0f / (__expf(2.0f * (a0 + b0)) + 1.0f);
      float c1 = 1.0f - 2.0f / (__expf(2.0f * (a1 + b1)) + 1.0f);
      float c2 = 1.0f - 2.0f / (__expf(2.0f * (a2 + b2)) + 1.0f);
      float c3 = 1.0f - 2.0f / (__expf(2.0f * (a3 + b3)) + 1.0f);
      unsigned long long uvp = __builtin_nontemporal_load(
          (const unsigned long long*)&u[rowSelf * 128 + col]);
      unsigned long long hvp = __builtin_nontemporal_load(
          (const unsigned long long*)&h[rowSelf * 128 + col]);
      float u0 = bflo((unsigned)uvp), u1 = bfhi((unsigned)uvp);
      float u2 = bflo((unsigned)(uvp >> 32)), u3 = bfhi((unsigned)(uvp >> 32));
      float h0 = bflo((unsigned)hvp), h1 = bfhi((unsigned)hvp);
      float h2 = bflo((unsigned)(hvp >> 32)), h3 = bfhi((unsigned)(hvp >> 32));
      float n0 = u0 * h0 + (1.0f - u0) * c0;
      float n1 = u1 * h1 + (1.0f - u1) * c1;
      float n2 = u2 * h2 + (1.0f - u2) * c2;
      float n3 = u3 * h3 + (1.0f - u3) * c3;
      unsigned lo = (unsigned)f2bf(n0) | ((unsigned)f2bf(n1) << 16);
      unsigned hi = (unsigned)f2bf(n2) | ((unsigned)f2bf(n3) << 16);
      __builtin_nontemporal_store(((unsigned long long)hi << 32) | lo,
                                  (unsigned long long*)&h[rowSelf * 128 + col]);
    }
  }
}

// ---------------- BatchNorm stats ----------------

__global__ __launch_bounds__(256) void bn_stats_kernel(const unsigned short* __restrict__ h,
                                                       float* __restrict__ sums) {
  __shared__ float ls[512];
  int tid = threadIdx.x;
  float s = 0.f, sq = 0.f;
  for (size_t idx = (size_t)blockIdx.x * 256 + tid; idx < (size_t)TOTAL * HH;
       idx += (size_t)gridDim.x * 256) {
    float v = bf2f(h[idx]);
    s += v; sq += v * v;
  }
  ls[tid] = s; ls[256 + tid] = sq;
  __syncthreads();
  if (tid < 128) {
    atomicAdd(&sums[tid], ls[tid] + ls[tid + 128]);
    atomicAdd(&sums[128 + tid], ls[256 + tid] + ls[256 + tid + 128]);
  }
}

// ---------------- fused BN -> relu -> lin_out -> log_softmax ----------------

__global__ __launch_bounds__(256) void final_kernel(const unsigned short* __restrict__ h,
                                                    const float* __restrict__ sums,
                                                    const float* __restrict__ gamma,
                                                    const float* __restrict__ beta,
                                                    const float* __restrict__ Wout,
                                                    const float* __restrict__ bout,
                                                    float* __restrict__ out) {
  int wid = threadIdx.x >> 6, lane = threadIdx.x & 63;
  int row = blockIdx.x * 4 + wid; // node-row (n*8+bb order)
  if (row >= TOTAL) return;
  const float inv = 1.0f / (float)TOTAL;
  float p0 = 0.f, p1 = 0.f, p2 = 0.f, p3 = 0.f;
#pragma unroll
  for (int jj = 0; jj < 2; jj++) {
    int j = lane + jj * 64;
    float mean = sums[j] * inv;
    float var = sums[128 + j] * inv - mean * mean;
    float hn = (bf2f(h[(size_t)row * HH + j]) - mean) * rsqrtf(var + 1e-5f) * gamma[j] + beta[j];
    hn = fmaxf(hn, 0.0f);
    p0 += hn * Wout[j * 4 + 0];
    p1 += hn * Wout[j * 4 + 1];
    p2 += hn * Wout[j * 4 + 2];
    p3 += hn * Wout[j * 4 + 3];
  }
  for (int off = 32; off; off >>= 1) {
    p0 += __shfl_down(p0, off);
    p1 += __shfl_down(p1, off);
    p2 += __shfl_down(p2, off);
    p3 += __shfl_down(p3, off);
  }
  if (lane == 0) {
    p0 += bout[0]; p1 += bout[1]; p2 += bout[2]; p3 += bout[3];
    float m = fmaxf(fmaxf(p0, p1), fmaxf(p2, p3));
    float e = __expf(p0 - m) + __expf(p1 - m) + __expf(p2 - m) + __expf(p3 - m);
    float lse = m + __logf(e);
    int bb = row & 7, n = row >> 3;
    float* o = out + ((size_t)bb * NN + n) * 4;
    o[0] = p0 - lse; o[1] = p1 - lse; o[2] = p2 - lse; o[3] = p3 - lse;
  }
}

// ---------------- launcher ----------------

extern "C" void kernel_launch(void* const* d_in, const int* in_sizes, int n_in,
                              void* d_out, int out_size, void* d_ws, size_t ws_size,
                              hipStream_t stream) {
  const float* x_seq = (const float*)d_in[0];
  const int* ei      = (const int*)d_in[1];
  const float* ew    = (const float*)d_in[2];
  const float* Win   = (const float*)d_in[3];
  const float* bin   = (const float*)d_in[4];
  const float* convW = (const float*)d_in[5];
  const float* convB = (const float*)d_in[6];
  const float* gamma = (const float*)d_in[7];
  const float* beta  = (const float*)d_in[8];
  const float* Wout  = (const float*)d_in[9];
  const float* bout  = (const float*)d_in[10];
  float* out = (float*)d_out;

  char* ws = (char*)d_ws;
  size_t off = 0;
  auto alloc = [&](size_t bytes) {
    void* p = ws + off;
    off += (bytes + 1023) & ~(size_t)1023;
    return p;
  };
  float* deg     = (float*)alloc(NN * 4);
  float* dis     = (float*)alloc(NN * 4);
  int*   cnt     = (int*)alloc(NN * 4);
  int*   offs    = (int*)alloc((NN + 1) * 4);
  int*   cursor  = (int*)alloc(NN * 4);
  int*   csr_src = (int*)alloc(EE * 4);
  float* csr_w   = (float*)alloc(EE * 4);
  float* sums    = (float*)alloc(256 * 4);
  int*   qbase   = (int*)alloc(24 * 16 * 4);   // 24 layer-steps x (8 gates + 8 cand) counters
  unsigned short* Wp = (unsigned short*)alloc(6 * 32768 * 2);  // packed conv weights
  const size_t NH = (size_t)TOTAL * HH; // 5,120,000
  unsigned short* h0 = (unsigned short*)alloc(NH * 2);
  unsigned short* h1 = (unsigned short*)alloc(NH * 2);
  unsigned short* xt = (unsigned short*)alloc(NH * 2);
  unsigned short* rh = (unsigned short*)alloc(NH * 2);
  unsigned short* ub = (unsigned short*)alloc(NH * 2);
  unsigned short* GR = (unsigned short*)alloc(NH * 2);
  unsigned short* GU = (unsigned short*)alloc(NH * 2);
  unsigned short* Cpre = GR;  // candidate pre-scatter reuses GR

  hipMemsetAsync(deg, 0, NN * 4, stream);
  hipMemsetAsync(cnt, 0, NN * 4, stream);
  hipMemsetAsync(cursor, 0, NN * 4, stream);
  hipMemsetAsync(sums, 0, 256 * 4, stream);
  hipMemsetAsync(qbase, 0, 24 * 16 * 4, stream);
  hipMemsetAsync(h0, 0, NH * 2, stream);
  hipMemsetAsync(h1, 0, NH * 2, stream);

  deg_cnt_kernel<<<(EE + 255) / 256, 256, 0, stream>>>(ei, ew, deg, cnt);
  dis_kernel<<<(NN + 255) / 256, 256, 0, stream>>>(deg, dis);
  scan_kernel<<<1, 256, 0, stream>>>(cnt, offs);
  fill_csr_kernel<<<(EE + 255) / 256, 256, 0, stream>>>(ei, ew, dis, offs, cursor, csr_src, csr_w);
  prepack_kernel<<<24576 / 256, 256, 0, stream>>>(convW, Wp);

  for (int t = 0; t < SS; t++) {
    lin_in_kernel<<<TOTAL * 32 / 256, 256, 0, stream>>>(x_seq, Win, bin, xt, t);
    for (int l = 0; l < 2; l++) {
      int ls = t * 2 + l;
      const unsigned short* xin = (l == 0) ? xt : h0;
      unsigned short* h = (l == 0) ? h0 : h1;
      const unsigned short* Wg = Wp + (size_t)(l * 3) * 32768;
      const unsigned short* Wc = Wp + (size_t)(l * 3 + 2) * 32768;
      const float* bRU = convB + (size_t)l * 3 * HH;
      const float* bC  = bRU + 2 * HH;
      gemm_mfma<4><<<TOTAL / 64, 256, 0, stream>>>(xin, h, Wg, GR, GU);
      scatter_gates_kernel<<<2048, 256, 0, stream>>>(GR, GU, offs, csr_src, csr_w,
                                                     dis, bRU, h, rh, ub, qbase + ls * 16);
      gemm_mfma<2><<<TOTAL / 64, 256, 0, stream>>>(xin, rh, Wc, Cpre, Cpre);
      scatter_c_update_kernel<<<2048, 256, 0, stream>>>(Cpre, offs, csr_src, csr_w,
                                                        dis, bC, ub, h, qbase + ls * 16 + 8);
    }
  }

  bn_stats_kernel<<<256, 256, 0, stream>>>(h1, sums);
  final_kernel<<<TOTAL / 4, 256, 0, stream>>>(h1, sums, gamma, beta, Wout, bout, out);
}

// Round 6
// 2387.223 us; speedup vs baseline: 6.0246x; 6.0246x over previous
//
#include <hip/hip_runtime.h>
#include <cstdint>
#include <cstddef>

#define NN 5000     // nodes per batch block
#define EE 40000    // edges per batch block
#define BATCH 8
#define SS 12
#define FF 16
#define HH 128
#define TOTAL 40000 // BATCH*NN
#define CC 4

typedef __attribute__((ext_vector_type(8))) short short8;   // 8 bf16 (4 VGPRs)
typedef __attribute__((ext_vector_type(4))) float f32x4;    // 4 fp32

__device__ __forceinline__ unsigned short f2bf(float f) {
  union { float f; unsigned u; } v; v.f = f;
  unsigned r = v.u + 0x7fff + ((v.u >> 16) & 1);  // RTNE
  return (unsigned short)(r >> 16);
}
__device__ __forceinline__ float bf2f(unsigned short b) {
  union { unsigned u; float f; } v; v.u = ((unsigned)b) << 16;
  return v.f;
}
__device__ __forceinline__ float bflo(unsigned v) {
  union { unsigned u; float f; } x; x.u = v << 16; return x.f;
}
__device__ __forceinline__ float bfhi(unsigned v) {
  union { unsigned u; float f; } x; x.u = v & 0xffff0000u; return x.f;
}

// ---------------- graph preprocessing (once per launch) ----------------

__global__ void deg_cnt_kernel(const int* __restrict__ ei, const float* __restrict__ ew,
                               float* __restrict__ deg, int* __restrict__ cnt) {
  int e = blockIdx.x * 256 + threadIdx.x;
  if (e < EE) {
    int col = ei[EE + e];
    atomicAdd(&deg[col], ew[e]);
    atomicAdd(&cnt[col], 1);
  }
}

__global__ void dis_kernel(const float* __restrict__ deg, float* __restrict__ dis) {
  int n = blockIdx.x * 256 + threadIdx.x;
  if (n < NN) dis[n] = rsqrtf(deg[n] + 1.0f);  // +1: self-loop weight
}

__global__ void scan_kernel(const int* __restrict__ cnt, int* __restrict__ offs) {
  __shared__ int part[256];
  const int CH = (NN + 255) / 256; // 20
  int tid = threadIdx.x;
  int base = tid * CH;
  int s = 0;
  for (int i = 0; i < CH; i++) { int idx = base + i; if (idx < NN) s += cnt[idx]; }
  part[tid] = s;
  __syncthreads();
  for (int off = 1; off < 256; off <<= 1) {
    int v = (tid >= off) ? part[tid - off] : 0;
    __syncthreads();
    part[tid] += v;
    __syncthreads();
  }
  int run = (tid == 0) ? 0 : part[tid - 1];
  for (int i = 0; i < CH; i++) {
    int idx = base + i;
    if (idx < NN) { offs[idx] = run; run += cnt[idx]; }
  }
  if (tid == 255) offs[NN] = run;
}

__global__ void fill_csr_kernel(const int* __restrict__ ei, const float* __restrict__ ew,
                                const float* __restrict__ dis, const int* __restrict__ offs,
                                int* __restrict__ cursor, int* __restrict__ csr_src,
                                float* __restrict__ csr_w) {
  int e = blockIdx.x * 256 + threadIdx.x;
  if (e < EE) {
    int row = ei[e], col = ei[EE + e];
    int pos = offs[col] + atomicAdd(&cursor[col], 1);
    csr_src[pos] = row;
    csr_w[pos] = dis[row] * ew[e] * dis[col];
  }
}

// ---------------- weight prepack: fp32 [k][n] -> bf16 MFMA b-frag order ----------------

__global__ void prepack_kernel(const float* __restrict__ convW, unsigned short* __restrict__ Wp) {
  int idx = blockIdx.x * 256 + threadIdx.x;  // 6*8*8*64 = 24576
  int lane = idx & 63;
  int ks = (idx >> 6) & 7;
  int nt = (idx >> 9) & 7;
  int g = idx >> 12;
  const float* W = convW + (size_t)g * 256 * 128;
  int n = nt * 16 + (lane & 15);
  int k0 = ks * 32 + (lane >> 4) * 8;
  unsigned short v[8];
#pragma unroll
  for (int j = 0; j < 8; j++) v[j] = f2bf(W[(size_t)(k0 + j) * 128 + n]);
  *(uint4*)(Wp + (size_t)idx * 8) = *(const uint4*)v;
}

// ---------------- lin_in: xt = relu(x_t @ Win + bin), bf16 out, row = n*8+bb ----------------

__global__ __launch_bounds__(256) void lin_in_kernel(const float* __restrict__ x_seq,
                                                     const float* __restrict__ W,
                                                     const float* __restrict__ b,
                                                     unsigned short* __restrict__ xt, int t) {
  int idx = blockIdx.x * 256 + threadIdx.x;   // over TOTAL*32
  int row = idx >> 5, fq = idx & 31;          // feats 4fq..4fq+3
  int n = row >> 3, bb = row & 7;
  const float* xp = x_seq + (((size_t)bb * SS + t) * NN + n) * FF;
  float4 a = *(const float4*)&b[fq * 4];
#pragma unroll
  for (int ff = 0; ff < FF; ff++) {
    float xv = xp[ff];
    float4 w = *(const float4*)&W[ff * HH + fq * 4];
    a.x += xv * w.x; a.y += xv * w.y; a.z += xv * w.z; a.w += xv * w.w;
  }
  uint2 o;
  o.x = (unsigned)f2bf(fmaxf(a.x, 0.f)) | ((unsigned)f2bf(fmaxf(a.y, 0.f)) << 16);
  o.y = (unsigned)f2bf(fmaxf(a.z, 0.f)) | ((unsigned)f2bf(fmaxf(a.w, 0.f)) << 16);
  *(uint2*)&xt[(size_t)row * 128 + fq * 4] = o;
}

// ---------------- bf16 MFMA GEMM ----------------

template <int NTW>
__global__ __launch_bounds__(256) void gemm_mfma(const unsigned short* __restrict__ A1,
                                                 const unsigned short* __restrict__ A2,
                                                 const unsigned short* __restrict__ Wp,
                                                 unsigned short* __restrict__ outR,
                                                 unsigned short* __restrict__ outU) {
  __shared__ unsigned short As[64 * 264];  // 64 rows x 256 K, +8 pad
  int rowBase = blockIdx.x * 64;
  int tid = threadIdx.x;
  for (int c = tid; c < 2048; c += 256) {
    int row = c >> 5; int rest = c & 31; int half = rest >> 4; int sub = rest & 15;
    const unsigned short* src = (half ? A2 : A1) + ((size_t)(rowBase + row) * 128 + sub * 8);
    *(uint4*)&As[row * 264 + half * 128 + sub * 8] = *(const uint4*)src;
  }
  __syncthreads();
  int wv = tid >> 6, lane = tid & 63;
  int m = lane & 15, q = lane >> 4;
  f32x4 acc[4][NTW];
#pragma unroll
  for (int i = 0; i < 4; i++)
#pragma unroll
    for (int j = 0; j < NTW; j++) acc[i][j] = (f32x4)(0.0f);
  const unsigned short* wbase = Wp + ((size_t)(wv * NTW) * 8 * 64 + lane) * 8;
#pragma unroll
  for (int ks = 0; ks < 8; ks++) {
    short8 a[4];
#pragma unroll
    for (int mt = 0; mt < 4; mt++)
      a[mt] = *(const short8*)&As[(mt * 16 + m) * 264 + ks * 32 + q * 8];
#pragma unroll
    for (int nt = 0; nt < NTW; nt++) {
      short8 b = *(const short8*)(wbase + (size_t)(nt * 8 + ks) * 64 * 8);
#pragma unroll
      for (int mt = 0; mt < 4; mt++)
        acc[mt][nt] = __builtin_amdgcn_mfma_f32_16x16x32_bf16(a[mt], b, acc[mt][nt], 0, 0, 0);
    }
  }
#pragma unroll
  for (int mt = 0; mt < 4; mt++)
#pragma unroll
    for (int nt = 0; nt < NTW; nt++) {
      int col = (wv * NTW + nt) * 16 + m;
      unsigned short* op = (col < 128) ? (outR + col) : (outU + (col - 128));
#pragma unroll
      for (int i = 0; i < 4; i++) {
        int row = rowBase + mt * 16 + q * 4 + i;
        op[(size_t)row * 128] = f2bf(acc[mt][nt][i]);
      }
    }
}

// ---------------- gates aggregation: batch-major static chunking ----------------
// grid (1250, 8): blockIdx.y = batch chunk (launch-order contiguous -> the per-batch
// 2.56 MB GR|GU slice stays resident in every XCD's L2). Wave = one node: lanes 0-31
// gather GR cols lane*4, lanes 32-63 GU. Block = 4 nodes.

__global__ __launch_bounds__(256) void scatter_gates_kernel(
    const unsigned short* __restrict__ GR, const unsigned short* __restrict__ GU,
    const int* __restrict__ offs, const int* __restrict__ csr_src,
    const float* __restrict__ csr_w, const float* __restrict__ dis,
    const float* __restrict__ bRU, const unsigned short* __restrict__ h,
    unsigned short* __restrict__ rh, unsigned short* __restrict__ u) {
  int bb = blockIdx.y;
  int tid = threadIdx.x;
  int wv = tid >> 6, lane = tid & 63;
  int half = lane >> 5;
  int col = (lane & 31) << 2;
  int n = blockIdx.x * 4 + wv;
  const unsigned short* G = half ? GU : GR;
  const float* bias = bRU + half * 128 + col;
  float b0 = bias[0], b1 = bias[1], b2 = bias[2], b3 = bias[3];
  float sn = dis[n]; sn *= sn;
  size_t rowSelf = (size_t)(n << 3) + bb;
  uint2 gv = *(const uint2*)&G[rowSelf * 128 + col];
  float a0 = sn * bflo(gv.x), a1 = sn * bfhi(gv.x);
  float a2 = sn * bflo(gv.y), a3 = sn * bfhi(gv.y);
  int e0 = offs[n], e1 = offs[n + 1];
  int e = e0;
  for (; e + 1 < e1; e += 2) {
    int s0 = csr_src[e], s1 = csr_src[e + 1];
    float w0 = csr_w[e], w1 = csr_w[e + 1];
    uint2 ga = *(const uint2*)&G[(((size_t)s0 << 3) + bb) * 128 + col];
    uint2 gb = *(const uint2*)&G[(((size_t)s1 << 3) + bb) * 128 + col];
    a0 += w0 * bflo(ga.x); a1 += w0 * bfhi(ga.x);
    a2 += w0 * bflo(ga.y); a3 += w0 * bfhi(ga.y);
    a0 += w1 * bflo(gb.x); a1 += w1 * bfhi(gb.x);
    a2 += w1 * bflo(gb.y); a3 += w1 * bfhi(gb.y);
  }
  if (e < e1) {
    int s0 = csr_src[e];
    float w0 = csr_w[e];
    uint2 ga = *(const uint2*)&G[(((size_t)s0 << 3) + bb) * 128 + col];
    a0 += w0 * bflo(ga.x); a1 += w0 * bfhi(ga.x);
    a2 += w0 * bflo(ga.y); a3 += w0 * bfhi(ga.y);
  }
  float v0 = 1.0f / (1.0f + __expf(-(a0 + b0)));
  float v1 = 1.0f / (1.0f + __expf(-(a1 + b1)));
  float v2 = 1.0f / (1.0f + __expf(-(a2 + b2)));
  float v3 = 1.0f / (1.0f + __expf(-(a3 + b3)));
  if (half == 0) {
    unsigned long long hv = __builtin_nontemporal_load(
        (const unsigned long long*)&h[rowSelf * 128 + col]);
    v0 *= bflo((unsigned)hv); v1 *= bfhi((unsigned)hv);
    v2 *= bflo((unsigned)(hv >> 32)); v3 *= bfhi((unsigned)(hv >> 32));
    unsigned lo = (unsigned)f2bf(v0) | ((unsigned)f2bf(v1) << 16);
    unsigned hi = (unsigned)f2bf(v2) | ((unsigned)f2bf(v3) << 16);
    __builtin_nontemporal_store(((unsigned long long)hi << 32) | lo,
                                (unsigned long long*)&rh[rowSelf * 128 + col]);
  } else {
    unsigned lo = (unsigned)f2bf(v0) | ((unsigned)f2bf(v1) << 16);
    unsigned hi = (unsigned)f2bf(v2) | ((unsigned)f2bf(v3) << 16);
    __builtin_nontemporal_store(((unsigned long long)hi << 32) | lo,
                                (unsigned long long*)&u[rowSelf * 128 + col]);
  }
}

// ---------------- candidate aggregation + GRU update: batch-major static chunking ----------------
// grid (625, 8): blockIdx.y = batch chunk (1.28 MB slice). Wave = 2 nodes x 32 lanes.

__global__ __launch_bounds__(256) void scatter_c_update_kernel(
    const unsigned short* __restrict__ Cp, const int* __restrict__ offs,
    const int* __restrict__ csr_src, const float* __restrict__ csr_w,
    const float* __restrict__ dis, const float* __restrict__ bC,
    const unsigned short* __restrict__ u, unsigned short* __restrict__ h) {
  int bb = blockIdx.y;
  int tid = threadIdx.x;
  int wv = tid >> 6, lane = tid & 63;
  int nh = lane >> 5;             // node-in-pair
  int col = (lane & 31) << 2;
  int n = blockIdx.x * 8 + wv * 2 + nh;
  const float* bp = bC + col;
  float b0 = bp[0], b1 = bp[1], b2 = bp[2], b3 = bp[3];
  float sn = dis[n]; sn *= sn;
  size_t rowSelf = (size_t)(n << 3) + bb;
  uint2 gv = *(const uint2*)&Cp[rowSelf * 128 + col];
  float a0 = sn * bflo(gv.x), a1 = sn * bfhi(gv.x);
  float a2 = sn * bflo(gv.y), a3 = sn * bfhi(gv.y);
  int e0 = offs[n], e1 = offs[n + 1];
  int e = e0;
  for (; e + 1 < e1; e += 2) {
    int s0 = csr_src[e], s1 = csr_src[e + 1];
    float w0 = csr_w[e], w1 = csr_w[e + 1];
    uint2 ga = *(const uint2*)&Cp[(((size_t)s0 << 3) + bb) * 128 + col];
    uint2 gb = *(const uint2*)&Cp[(((size_t)s1 << 3) + bb) * 128 + col];
    a0 += w0 * bflo(ga.x); a1 += w0 * bfhi(ga.x);
    a2 += w0 * bflo(ga.y); a3 += w0 * bfhi(ga.y);
    a0 += w1 * bflo(gb.x); a1 += w1 * bfhi(gb.x);
    a2 += w1 * bflo(gb.y); a3 += w1 * bfhi(gb.y);
  }
  if (e < e1) {
    int s0 = csr_src[e];
    float w0 = csr_w[e];
    uint2 ga = *(const uint2*)&Cp[(((size_t)s0 << 3) + bb) * 128 + col];
    a0 += w0 * bflo(ga.x); a1 += w0 * bfhi(ga.x);
    a2 += w0 * bflo(ga.y); a3 += w0 * bfhi(ga.y);
  }
  float c0 = 1.0f - 2.0f / (__expf(2.0f * (a0 + b0)) + 1.0f);
  float c1 = 1.0f - 2.0f / (__expf(2.0f * (a1 + b1)) + 1.0f);
  float c2 = 1.0f - 2.0f / (__expf(2.0f * (a2 + b2)) + 1.0f);
  float c3 = 1.0f - 2.0f / (__expf(2.0f * (a3 + b3)) + 1.0f);
  unsigned long long uvp = __builtin_nontemporal_load(
      (const unsigned long long*)&u[rowSelf * 128 + col]);
  unsigned long long hvp = __builtin_nontemporal_load(
      (const unsigned long long*)&h[rowSelf * 128 + col]);
  float u0 = bflo((unsigned)uvp), u1 = bfhi((unsigned)uvp);
  float u2 = bflo((unsigned)(uvp >> 32)), u3 = bfhi((unsigned)(uvp >> 32));
  float h0 = bflo((unsigned)hvp), h1 = bfhi((unsigned)hvp);
  float h2 = bflo((unsigned)(hvp >> 32)), h3 = bfhi((unsigned)(hvp >> 32));
  float n0 = u0 * h0 + (1.0f - u0) * c0;
  float n1 = u1 * h1 + (1.0f - u1) * c1;
  float n2 = u2 * h2 + (1.0f - u2) * c2;
  float n3 = u3 * h3 + (1.0f - u3) * c3;
  unsigned lo = (unsigned)f2bf(n0) | ((unsigned)f2bf(n1) << 16);
  unsigned hi = (unsigned)f2bf(n2) | ((unsigned)f2bf(n3) << 16);
  __builtin_nontemporal_store(((unsigned long long)hi << 32) | lo,
                              (unsigned long long*)&h[rowSelf * 128 + col]);
}

// ---------------- BatchNorm stats ----------------

__global__ __launch_bounds__(256) void bn_stats_kernel(const unsigned short* __restrict__ h,
                                                       float* __restrict__ sums) {
  __shared__ float ls[512];
  int tid = threadIdx.x;
  float s = 0.f, sq = 0.f;
  for (size_t idx = (size_t)blockIdx.x * 256 + tid; idx < (size_t)TOTAL * HH;
       idx += (size_t)gridDim.x * 256) {
    float v = bf2f(h[idx]);
    s += v; sq += v * v;
  }
  ls[tid] = s; ls[256 + tid] = sq;
  __syncthreads();
  if (tid < 128) {
    atomicAdd(&sums[tid], ls[tid] + ls[tid + 128]);
    atomicAdd(&sums[128 + tid], ls[256 + tid] + ls[256 + tid + 128]);
  }
}

// ---------------- fused BN -> relu -> lin_out -> log_softmax ----------------

__global__ __launch_bounds__(256) void final_kernel(const unsigned short* __restrict__ h,
                                                    const float* __restrict__ sums,
                                                    const float* __restrict__ gamma,
                                                    const float* __restrict__ beta,
                                                    const float* __restrict__ Wout,
                                                    const float* __restrict__ bout,
                                                    float* __restrict__ out) {
  int wid = threadIdx.x >> 6, lane = threadIdx.x & 63;
  int row = blockIdx.x * 4 + wid; // node-row (n*8+bb order)
  if (row >= TOTAL) return;
  const float inv = 1.0f / (float)TOTAL;
  float p0 = 0.f, p1 = 0.f, p2 = 0.f, p3 = 0.f;
#pragma unroll
  for (int jj = 0; jj < 2; jj++) {
    int j = lane + jj * 64;
    float mean = sums[j] * inv;
    float var = sums[128 + j] * inv - mean * mean;
    float hn = (bf2f(h[(size_t)row * HH + j]) - mean) * rsqrtf(var + 1e-5f) * gamma[j] + beta[j];
    hn = fmaxf(hn, 0.0f);
    p0 += hn * Wout[j * 4 + 0];
    p1 += hn * Wout[j * 4 + 1];
    p2 += hn * Wout[j * 4 + 2];
    p3 += hn * Wout[j * 4 + 3];
  }
  for (int off = 32; off; off >>= 1) {
    p0 += __shfl_down(p0, off);
    p1 += __shfl_down(p1, off);
    p2 += __shfl_down(p2, off);
    p3 += __shfl_down(p3, off);
  }
  if (lane == 0) {
    p0 += bout[0]; p1 += bout[1]; p2 += bout[2]; p3 += bout[3];
    float m = fmaxf(fmaxf(p0, p1), fmaxf(p2, p3));
    float e = __expf(p0 - m) + __expf(p1 - m) + __expf(p2 - m) + __expf(p3 - m);
    float lse = m + __logf(e);
    int bb = row & 7, n = row >> 3;
    float* o = out + ((size_t)bb * NN + n) * 4;
    o[0] = p0 - lse; o[1] = p1 - lse; o[2] = p2 - lse; o[3] = p3 - lse;
  }
}

// ---------------- launcher ----------------

extern "C" void kernel_launch(void* const* d_in, const int* in_sizes, int n_in,
                              void* d_out, int out_size, void* d_ws, size_t ws_size,
                              hipStream_t stream) {
  const float* x_seq = (const float*)d_in[0];
  const int* ei      = (const int*)d_in[1];
  const float* ew    = (const float*)d_in[2];
  const float* Win   = (const float*)d_in[3];
  const float* bin   = (const float*)d_in[4];
  const float* convW = (const float*)d_in[5];
  const float* convB = (const float*)d_in[6];
  const float* gamma = (const float*)d_in[7];
  const float* beta  = (const float*)d_in[8];
  const float* Wout  = (const float*)d_in[9];
  const float* bout  = (const float*)d_in[10];
  float* out = (float*)d_out;

  char* ws = (char*)d_ws;
  size_t off = 0;
  auto alloc = [&](size_t bytes) {
    void* p = ws + off;
    off += (bytes + 1023) & ~(size_t)1023;
    return p;
  };
  float* deg     = (float*)alloc(NN * 4);
  float* dis     = (float*)alloc(NN * 4);
  int*   cnt     = (int*)alloc(NN * 4);
  int*   offs    = (int*)alloc((NN + 1) * 4);
  int*   cursor  = (int*)alloc(NN * 4);
  int*   csr_src = (int*)alloc(EE * 4);
  float* csr_w   = (float*)alloc(EE * 4);
  float* sums    = (float*)alloc(256 * 4);
  unsigned short* Wp = (unsigned short*)alloc(6 * 32768 * 2);  // packed conv weights
  const size_t NH = (size_t)TOTAL * HH; // 5,120,000
  unsigned short* h0 = (unsigned short*)alloc(NH * 2);
  unsigned short* h1 = (unsigned short*)alloc(NH * 2);
  unsigned short* xt = (unsigned short*)alloc(NH * 2);
  unsigned short* rh = (unsigned short*)alloc(NH * 2);
  unsigned short* ub = (unsigned short*)alloc(NH * 2);
  unsigned short* GR = (unsigned short*)alloc(NH * 2);
  unsigned short* GU = (unsigned short*)alloc(NH * 2);
  unsigned short* Cpre = GR;  // candidate pre-scatter reuses GR

  hipMemsetAsync(deg, 0, NN * 4, stream);
  hipMemsetAsync(cnt, 0, NN * 4, stream);
  hipMemsetAsync(cursor, 0, NN * 4, stream);
  hipMemsetAsync(sums, 0, 256 * 4, stream);
  hipMemsetAsync(h0, 0, NH * 2, stream);
  hipMemsetAsync(h1, 0, NH * 2, stream);

  deg_cnt_kernel<<<(EE + 255) / 256, 256, 0, stream>>>(ei, ew, deg, cnt);
  dis_kernel<<<(NN + 255) / 256, 256, 0, stream>>>(deg, dis);
  scan_kernel<<<1, 256, 0, stream>>>(cnt, offs);
  fill_csr_kernel<<<(EE + 255) / 256, 256, 0, stream>>>(ei, ew, dis, offs, cursor, csr_src, csr_w);
  prepack_kernel<<<24576 / 256, 256, 0, stream>>>(convW, Wp);

  for (int t = 0; t < SS; t++) {
    lin_in_kernel<<<TOTAL * 32 / 256, 256, 0, stream>>>(x_seq, Win, bin, xt, t);
    for (int l = 0; l < 2; l++) {
      const unsigned short* xin = (l == 0) ? xt : h0;
      unsigned short* h = (l == 0) ? h0 : h1;
      const unsigned short* Wg = Wp + (size_t)(l * 3) * 32768;
      const unsigned short* Wc = Wp + (size_t)(l * 3 + 2) * 32768;
      const float* bRU = convB + (size_t)l * 3 * HH;
      const float* bC  = bRU + 2 * HH;
      gemm_mfma<4><<<TOTAL / 64, 256, 0, stream>>>(xin, h, Wg, GR, GU);
      scatter_gates_kernel<<<dim3(NN / 4, 8), 256, 0, stream>>>(GR, GU, offs, csr_src, csr_w,
                                                                dis, bRU, h, rh, ub);
      gemm_mfma<2><<<TOTAL / 64, 256, 0, stream>>>(xin, rh, Wc, Cpre, Cpre);
      scatter_c_update_kernel<<<dim3(NN / 8, 8), 256, 0, stream>>>(Cpre, offs, csr_src, csr_w,
                                                                   dis, bC, ub, h);
    }
  }

  bn_stats_kernel<<<256, 256, 0, stream>>>(h1, sums);
  final_kernel<<<TOTAL / 4, 256, 0, stream>>>(h1, sums, gamma, beta, Wout, bout, out);
}